// Round 14
// baseline (42.153 us; speedup 1.0000x reference)
//
#include <hip/hip_runtime.h>
#include <hip/hip_bf16.h>
#include <math.h>

// S4 SSKernelNPLR, fully fused per-head. 1024 threads/block, ONE packed chain
// per thread: bins (tid, 2048-tid) via tan/cot mirror identity; tid0 carries
// (0, 1024). __launch_bounds__(1024,8) caps VGPR at 64 -> 2 blocks/CU =
// 32 waves/CU (occupancy cap, 2x the r13 latency hiding). Same total work.
//   phase 1: per-h pole params (dt-folded), un-duplicated: 10 floats/pole as
//            2 x float4 + 1 x float2 (3 broadcast LDS reads/pole/wave).
//   phase 2: Cauchy + Woodbury at 2049 rfft nodes, packed fp32 (compiler
//            v_pk_fma_f32, op_sel splats). One rcp per pole. tan/cot via HW
//            v_sin/v_cos (revolutions, < 0.25). In-register Hermitian
//            recombination -> Z in LDS.
//   phase 3: 2048-pt radix-2 DIF inverse FFT, two stages per barrier
//            (512 butterfly-quads, tid<512; co-resident block covers the
//            idle waves), on-the-fly HW twiddles. Final s=0 stage fused into
//            the output gather: out[tid]=z0+z1, out[tid+1024]=z0-z1 at
//            r0 = bitrev11(tid) (even), z0/z1 adjacent in padded LDS.
//   output: x[2m]=Re z[m]/M, x[2m+1]=Im z[m]/M, coalesced float2 stores.
// LDS ~20 KB; grid 512 x 1024 thr; 7 barriers.
// Dims hardcoded: H=512, N=64, R=1, CH=1, L=4096.

#define HH   512
#define NN   64
#define LLEN 4096
#define MM   2048
#define NTHREADS 1024
#define ZPAD(i) ((i) + ((i) >> 4))

typedef float v2f __attribute__((ext_vector_type(2)));

__device__ __forceinline__ float sinr(float r) { return __builtin_amdgcn_sinf(r); }  // sin(2*pi*r)
__device__ __forceinline__ float cosr(float r) { return __builtin_amdgcn_cosf(r); }
__device__ __forceinline__ float rcpf(float x) { return __builtin_amdgcn_rcpf(x); }

__device__ __forceinline__ void cauchy_step(
    const v2f tv, const v2f mwi, const v2f nr, const v2f wr2,
    const v2f v00r, const v2f v00i, const v2f v01r, const v2f v01i,
    const v2f v10r, const v2f v10i, const v2f v11,
    v2f& a00r, v2f& a00i, v2f& a01r, v2f& a01i,
    v2f& a10r, v2f& a10i, v2f& a11r, v2f& a11i)
{
    const v2f dim = __builtin_elementwise_fma(tv, (v2f){2.0f, 2.0f}, mwi); // 2t - wi
    const v2f den = __builtin_elementwise_fma(dim, dim, wr2);
    const float ip = rcpf(den.x * den.y);      // one rcp for both halves
    v2f inv; inv.x = den.y * ip; inv.y = den.x * ip;
    const v2f ur = nr * inv;
    const v2f ui = -(dim * inv);
    a00r = __builtin_elementwise_fma( v00r, ur, a00r);
    a00r = __builtin_elementwise_fma(-v00i, ui, a00r);
    a00i = __builtin_elementwise_fma( v00r, ui, a00i);
    a00i = __builtin_elementwise_fma( v00i, ur, a00i);
    a01r = __builtin_elementwise_fma( v01r, ur, a01r);
    a01r = __builtin_elementwise_fma(-v01i, ui, a01r);
    a01i = __builtin_elementwise_fma( v01r, ui, a01i);
    a01i = __builtin_elementwise_fma( v01i, ur, a01i);
    a10r = __builtin_elementwise_fma( v10r, ur, a10r);
    a10r = __builtin_elementwise_fma(-v10i, ui, a10r);
    a10i = __builtin_elementwise_fma( v10r, ui, a10i);
    a10i = __builtin_elementwise_fma( v10i, ur, a10i);
    a11r = __builtin_elementwise_fma( v11,  ur, a11r);
    a11i = __builtin_elementwise_fma( v11,  ui, a11i);
}

__device__ __forceinline__ void woodbury_K(
    const v2f tv,
    const v2f a00r, const v2f a00i, const v2f a01r, const v2f a01i,
    const v2f a10r, const v2f a10i, const v2f a11r, const v2f a11i,
    v2f& Kr, v2f& Ki)
{
    const v2f dr = a11r + 1.0f;
    const v2f di = a11i;
    const v2f dd = __builtin_elementwise_fma(dr, dr, di * di);
    v2f dinv; dinv.x = rcpf(dd.x); dinv.y = rcpf(dd.y);
    const v2f numr = a01r * a10r - a01i * a10i;
    const v2f numi = a01r * a10i + a01i * a10r;
    const v2f cr = (numr * dr + numi * di) * dinv;
    const v2f ci = (numi * dr - numr * di) * dinv;
    const v2f Wr = a00r - cr;
    const v2f Wi = a00i - ci;
    Kr = __builtin_elementwise_fma(-tv, Wi, Wr);   // K = W * (1 + i*t)
    Ki = __builtin_elementwise_fma( tv, Wr, Wi);
}

__global__ __launch_bounds__(NTHREADS, 8) void ssknplr_kernel(
    const float* __restrict__ log_dt,
    const float* __restrict__ w_re, const float* __restrict__ w_im,
    const float* __restrict__ B_re, const float* __restrict__ B_im,
    const float* __restrict__ P_re, const float* __restrict__ P_im,
    const float* __restrict__ C_re, const float* __restrict__ C_im,
    float* __restrict__ out)
{
    // UN-duplicated per-pole scalars (all v* dt-folded):
    // q0 = {-wi, -wr, wr2, v00r}; q1 = {v00i, v01r, v01i, v10r}; q2 = {v10i, v11}
    __shared__ float4 s_q0[NN];             // 1 KB
    __shared__ float4 s_q1[NN];             // 1 KB
    __shared__ float2 s_q2[NN];             // 0.5 KB
    __shared__ float2 s_Z[ZPAD(MM) + 1];    // ~17.4 KB padded spectrum

    const int h   = blockIdx.x;
    const int tid = threadIdx.x;

    // ---- phase 1: per-head pole data ----
    if (tid < NN) {
        const int n   = tid;
        const int idx = h * NN + n;
        const float dt = expf(log_dt[h]);
        const float wr = w_re[idx] * dt;
        const float wi = w_im[idx] * dt;
        const float Br = B_re[idx], Bi = B_im[idx];
        const float Pr = P_re[idx], Pi = P_im[idx];
        const float Cr = C_re[idx], Ci = C_im[idx];
        const float v00r = dt * (Br * Cr - Bi * Ci);
        const float v00i = dt * (Br * Ci + Bi * Cr);
        const float v01r = dt * (Br * Pr + Bi * Pi);   // B*conj(P)
        const float v01i = dt * (Bi * Pr - Br * Pi);
        const float v10r = dt * (Pr * Cr - Pi * Ci);
        const float v10i = dt * (Pr * Ci + Pi * Cr);
        const float v11  = dt * (Pr * Pr + Pi * Pi);
        s_q0[n] = make_float4(-wi, -wr, wr * wr, v00r);
        s_q1[n] = make_float4(v00i, v01r, v01i, v10r);
        s_q2[n] = make_float2(v10i, v11);
    }
    __syncthreads();

    // ---- phase 2: Cauchy + Woodbury, mirror-pair chain ----
    // bins (tid, 2048-tid); tid==0 -> (0, 1024) since bin 2048 is analytic.
    v2f tv;
    {
        const float rA = (float)tid * (1.0f / 8192.0f);   // < 0.125
        const float sA = sinr(rA), cA = cosr(rA);
        tv.x = sA * rcpf(cA);                             // tan
        tv.y = (tid == 0) ? 1.0f : cA * rcpf(sA);         // cot; tid0 -> bin 1024 (t=1)
    }

    v2f a00r = {0.f,0.f}, a00i = {0.f,0.f}, a01r = {0.f,0.f}, a01i = {0.f,0.f};
    v2f a10r = {0.f,0.f}, a10i = {0.f,0.f}, a11r = {0.f,0.f}, a11i = {0.f,0.f};

    #pragma unroll 4
    for (int n = 0; n < NN; ++n) {
        const float4 q0 = s_q0[n];
        const float4 q1 = s_q1[n];
        const float2 q2 = s_q2[n];
        // v2f splats: folded into VOP3P op_sel (no movs expected)
        const v2f mwi  = {q0.x, q0.x}, nr   = {q0.y, q0.y}, wr2 = {q0.z, q0.z};
        const v2f v00r = {q0.w, q0.w}, v00i = {q1.x, q1.x};
        const v2f v01r = {q1.y, q1.y}, v01i = {q1.z, q1.z};
        const v2f v10r = {q1.w, q1.w}, v10i = {q2.x, q2.x};
        const v2f v11  = {q2.y, q2.y};
        cauchy_step(tv, mwi, nr, wr2, v00r, v00i, v01r, v01i, v10r, v10i, v11,
                    a00r, a00i, a01r, a01i, a10r, a10i, a11r, a11i);
    }

    // ---- in-register Hermitian recombination -> Z ----
    {
        v2f Kr, Ki;
        woodbury_K(tv, a00r, a00i, a01r, a01i, a10r, a10i, a11r, a11i, Kr, Ki);
        if (tid == 0) {
            float sr = 0.f;
            for (int n = 0; n < NN; ++n) sr += s_q0[n].w;      // v00r
            const float KN = 0.5f * sr;                        // analytic Nyquist K[2048]
            s_Z[ZPAD(0)]    = make_float2(0.5f * (Kr.x + KN), 0.5f * (Kr.x - KN));
            s_Z[ZPAD(1024)] = make_float2(Kr.y, -Ki.y);        // Z[M/2] = conj(K[M/2])
        } else {
            const int k = tid, Mk = MM - tid;
            const float rk = (float)k * (1.0f / 4096.0f);      // < 0.25
            const float sk = sinr(rk), ck = cosr(rk);
            const float Pr = 0.5f * (Kr.x + Kr.y), Pi = 0.5f * (Ki.x - Ki.y);
            const float Dr = 0.5f * (Kr.x - Kr.y), Di = 0.5f * (Ki.x + Ki.y);
            const float al = sk * Dr + ck * Di;
            const float be = ck * Dr - sk * Di;
            s_Z[ZPAD(k)]  = make_float2(Pr - al, Pi + be);
            s_Z[ZPAD(Mk)] = make_float2(Pr + al, be - Pi);
        }
    }
    __syncthreads();

    // ---- phase 3: 2048-pt inverse FFT, radix-2 DIF, TWO stages per barrier ----
    // Rounds (10,9)(8,7)(6,5)(4,3)(2,1); stage 0 fused into the output.
    // 512 butterfly-quads -> tid<512; idle waves covered by co-resident block.
    for (int s = 10; s >= 1; s -= 2) {
        const int H = 1 << s;
        const int Q = H >> 1;
        const float scale = rcpf((float)(2 * H));           // exact pow2
        if (tid < 512) {
            const int b    = tid;
            const int j    = b & (Q - 1);
            const int base = ((b >> (s - 1)) << (s + 1)) + j;
            const int i0 = base, i1 = base + Q, i2 = base + H, i3 = base + H + Q;
            const float rev = (float)j * scale;             // < 0.25
            const float c  = cosr(rev);
            const float sn = sinr(rev);
            const float wbr = c * c - sn * sn;              // wB = wA^2
            const float wbi = 2.0f * c * sn;
            const float2 u0 = s_Z[ZPAD(i0)];
            const float2 u1 = s_Z[ZPAD(i1)];
            const float2 u2 = s_Z[ZPAD(i2)];
            const float2 u3 = s_Z[ZPAD(i3)];
            // level A (stage s): (i0,i2) with wA ; (i1,i3) with i*wA
            const float a0r = u0.x + u2.x, a0i = u0.y + u2.y;
            const float d0r = u0.x - u2.x, d0i = u0.y - u2.y;
            const float a1r = u1.x + u3.x, a1i = u1.y + u3.y;
            const float d1r = u1.x - u3.x, d1i = u1.y - u3.y;
            const float e0r = d0r * c  - d0i * sn, e0i = d0r * sn + d0i * c;
            const float e1r = -(d1r * sn) - d1i * c, e1i = d1r * c - d1i * sn;
            // level B (stage s-1): (i0,i1) and (i2,i3), both with wB
            s_Z[ZPAD(i0)] = make_float2(a0r + a1r, a0i + a1i);
            const float t0r = a0r - a1r, t0i = a0i - a1i;
            s_Z[ZPAD(i1)] = make_float2(t0r * wbr - t0i * wbi, t0r * wbi + t0i * wbr);
            s_Z[ZPAD(i2)] = make_float2(e0r + e1r, e0i + e1i);
            const float t1r = e0r - e1r, t1i = e0i - e1i;
            s_Z[ZPAD(i3)] = make_float2(t1r * wbr - t1i * wbi, t1r * wbi + t1i * wbr);
        }
        __syncthreads();
    }

    // ---- output with FUSED final stage ----
    // m = tid (bit10 clear) -> r0 = bitrev11(tid), bit0 clear;
    // m = tid+1024 -> r0|1.  X[r0] = Z[r0]+Z[r0+1], X[r0|1] = Z[r0]-Z[r0+1].
    {
        const float scale = 1.0f / (float)MM;
        const int r0 = (int)(__brev((unsigned)tid) >> 21);  // even
        const int zb = ZPAD(r0);                            // r0, r0+1 ZP-consecutive
        const float2 z0 = s_Z[zb + 0];
        const float2 z1 = s_Z[zb + 1];
        float2* o2 = (float2*)out + (size_t)h * MM;
        o2[tid]        = make_float2((z0.x + z1.x) * scale, (z0.y + z1.y) * scale);
        o2[tid + 1024] = make_float2((z0.x - z1.x) * scale, (z0.y - z1.y) * scale);
    }
}

extern "C" void kernel_launch(void* const* d_in, const int* in_sizes, int n_in,
                              void* d_out, int out_size, void* d_ws, size_t ws_size,
                              hipStream_t stream) {
    const float* log_dt = (const float*)d_in[0];
    const float* w_re   = (const float*)d_in[1];
    const float* w_im   = (const float*)d_in[2];
    const float* B_re   = (const float*)d_in[3];
    const float* B_im   = (const float*)d_in[4];
    const float* P_re   = (const float*)d_in[5];
    const float* P_im   = (const float*)d_in[6];
    const float* C_re   = (const float*)d_in[7];
    const float* C_im   = (const float*)d_in[8];
    float* out = (float*)d_out;

    ssknplr_kernel<<<dim3(HH), dim3(NTHREADS), 0, stream>>>(
        log_dt, w_re, w_im, B_re, B_im, P_re, P_im, C_re, C_im, out);
}

// Round 15
// 37.014 us; speedup vs baseline: 1.1389x; 1.1389x over previous
//
#include <hip/hip_runtime.h>
#include <hip/hip_bf16.h>
#include <math.h>

// S4 SSKernelNPLR, fully fused per-head. 256 threads/block, FOUR packed
// chains/thread in mirror pairs: k in {tid, 256+tid, 512+tid, 768+tid},
// each chain = bins (k, 2048-k) via tan/cot identity; tid0 chain A = (0,1024),
// Nyquist analytic. In-register Hermitian recombination (r13-verified).
// Rationale (r14 post-mortem): per-CU pole-broadcast LDS stream halves again
// (8 waves x 64 poles x 3 reads), 4 independent dep-chains cover latency at
// 2 waves/SIMD.
//   phase 1: per-h pole params (dt-folded), un-duplicated: 2xfloat4+1xfloat2.
//   phase 2: Cauchy + Woodbury, packed fp32; one rcp per pole per chain;
//            HW v_sin/v_cos twiddles (revolutions, < 0.25).
//   phase 3: 2048-pt inverse FFT as radix-8,8,8,4 (r8-VERIFIED structure):
//            8 pts/thread in registers, 4 LDS rounds, bitrev-gather output.
// LDS ~20 KB; grid 512 x 256 thr; 6 barriers.
// Dims hardcoded: H=512, N=64, R=1, CH=1, L=4096.

#define HH   512
#define NN   64
#define LLEN 4096
#define MM   2048
#define NTHREADS 256
#define ZP(i) ((i) + ((i) >> 4) + ((i) >> 8))

typedef float v2f __attribute__((ext_vector_type(2)));

__device__ __forceinline__ float sinr(float r) { return __builtin_amdgcn_sinf(r); }  // sin(2*pi*r)
__device__ __forceinline__ float cosr(float r) { return __builtin_amdgcn_cosf(r); }
__device__ __forceinline__ float rcpf(float x) { return __builtin_amdgcn_rcpf(x); }

__device__ __forceinline__ void cauchy_step(
    const v2f tv, const v2f mwi, const v2f nr, const v2f wr2,
    const v2f v00r, const v2f v00i, const v2f v01r, const v2f v01i,
    const v2f v10r, const v2f v10i, const v2f v11,
    v2f& a00r, v2f& a00i, v2f& a01r, v2f& a01i,
    v2f& a10r, v2f& a10i, v2f& a11r, v2f& a11i)
{
    const v2f dim = __builtin_elementwise_fma(tv, (v2f){2.0f, 2.0f}, mwi); // 2t - wi
    const v2f den = __builtin_elementwise_fma(dim, dim, wr2);
    const float ip = rcpf(den.x * den.y);      // one rcp for both halves
    v2f inv; inv.x = den.y * ip; inv.y = den.x * ip;
    const v2f ur = nr * inv;
    const v2f ui = -(dim * inv);
    a00r = __builtin_elementwise_fma( v00r, ur, a00r);
    a00r = __builtin_elementwise_fma(-v00i, ui, a00r);
    a00i = __builtin_elementwise_fma( v00r, ui, a00i);
    a00i = __builtin_elementwise_fma( v00i, ur, a00i);
    a01r = __builtin_elementwise_fma( v01r, ur, a01r);
    a01r = __builtin_elementwise_fma(-v01i, ui, a01r);
    a01i = __builtin_elementwise_fma( v01r, ui, a01i);
    a01i = __builtin_elementwise_fma( v01i, ur, a01i);
    a10r = __builtin_elementwise_fma( v10r, ur, a10r);
    a10r = __builtin_elementwise_fma(-v10i, ui, a10r);
    a10i = __builtin_elementwise_fma( v10r, ui, a10i);
    a10i = __builtin_elementwise_fma( v10i, ur, a10i);
    a11r = __builtin_elementwise_fma( v11,  ur, a11r);
    a11i = __builtin_elementwise_fma( v11,  ui, a11i);
}

__device__ __forceinline__ void woodbury_K(
    const v2f tv,
    const v2f a00r, const v2f a00i, const v2f a01r, const v2f a01i,
    const v2f a10r, const v2f a10i, const v2f a11r, const v2f a11i,
    v2f& Kr, v2f& Ki)
{
    const v2f dr = a11r + 1.0f;
    const v2f di = a11i;
    const v2f dd = __builtin_elementwise_fma(dr, dr, di * di);
    v2f dinv; dinv.x = rcpf(dd.x); dinv.y = rcpf(dd.y);
    const v2f numr = a01r * a10r - a01i * a10i;
    const v2f numi = a01r * a10i + a01i * a10r;
    const v2f cr = (numr * dr + numi * di) * dinv;
    const v2f ci = (numi * dr - numr * di) * dinv;
    const v2f Wr = a00r - cr;
    const v2f Wi = a00i - ci;
    Kr = __builtin_elementwise_fma(-tv, Wi, Wr);   // K = W * (1 + i*t)
    Ki = __builtin_elementwise_fma( tv, Wr, Wi);
}

// radix-8 DIF block on 8 register-resident points (r8-verified).
// W1 = e^{2pi i rev}; natural in, internally bitrev'd out per DIF.
__device__ __forceinline__ void radix8(float xr[8], float xi[8], const float rev)
{
    const float c   = cosr(rev), s = sinr(rev);
    const float w2r = c * c - s * s, w2i = 2.0f * c * s;   // W2 = W1^2
    const float w4r = w2r * w2r - w2i * w2i;               // W4 = W2^2
    const float w4i = 2.0f * w2r * w2i;
    const float RH  = 0.70710678118654752440f;
    const float cms = RH * (c - s), cps = RH * (c + s);    // W1*w8

    const float Ar0 = xr[0] + xr[4], Ai0 = xi[0] + xi[4];
    const float Ar1 = xr[1] + xr[5], Ai1 = xi[1] + xi[5];
    const float Ar2 = xr[2] + xr[6], Ai2 = xi[2] + xi[6];
    const float Ar3 = xr[3] + xr[7], Ai3 = xi[3] + xi[7];
    float dr, di;
    dr = xr[0] - xr[4]; di = xi[0] - xi[4];
    const float Br0 = dr * c - di * s,      Bi0 = dr * s + di * c;
    dr = xr[1] - xr[5]; di = xi[1] - xi[5];
    const float Br1 = dr * cms - di * cps,  Bi1 = dr * cps + di * cms;
    dr = xr[2] - xr[6]; di = xi[2] - xi[6];                     // * i*W1
    const float Br2 = -dr * s - di * c,     Bi2 = dr * c - di * s;
    dr = xr[3] - xr[7]; di = xi[3] - xi[7];                     // * W1*w8^3
    const float Br3 = -dr * cps - di * cms, Bi3 = dr * cms - di * cps;

    const float Cr0 = Ar0 + Ar2, Ci0 = Ai0 + Ai2;
    const float Cr1 = Ar1 + Ar3, Ci1 = Ai1 + Ai3;
    dr = Ar0 - Ar2; di = Ai0 - Ai2;
    const float Dr0 = dr * w2r - di * w2i,  Di0 = dr * w2i + di * w2r;
    dr = Ar1 - Ar3; di = Ai1 - Ai3;                             // * i*W2
    const float Dr1 = -dr * w2i - di * w2r, Di1 = dr * w2r - di * w2i;
    const float Er0 = Br0 + Br2, Ei0 = Bi0 + Bi2;
    const float Er1 = Br1 + Br3, Ei1 = Bi1 + Bi3;
    dr = Br0 - Br2; di = Bi0 - Bi2;
    const float Fr0 = dr * w2r - di * w2i,  Fi0 = dr * w2i + di * w2r;
    dr = Br1 - Br3; di = Bi1 - Bi3;
    const float Fr1 = -dr * w2i - di * w2r, Fi1 = dr * w2r - di * w2i;

    xr[0] = Cr0 + Cr1; xi[0] = Ci0 + Ci1;
    dr = Cr0 - Cr1; di = Ci0 - Ci1;
    xr[1] = dr * w4r - di * w4i; xi[1] = dr * w4i + di * w4r;
    xr[2] = Dr0 + Dr1; xi[2] = Di0 + Di1;
    dr = Dr0 - Dr1; di = Di0 - Di1;
    xr[3] = dr * w4r - di * w4i; xi[3] = dr * w4i + di * w4r;
    xr[4] = Er0 + Er1; xi[4] = Ei0 + Ei1;
    dr = Er0 - Er1; di = Ei0 - Ei1;
    xr[5] = dr * w4r - di * w4i; xi[5] = dr * w4i + di * w4r;
    xr[6] = Fr0 + Fr1; xi[6] = Fi0 + Fi1;
    dr = Fr0 - Fr1; di = Fi0 - Fi1;
    xr[7] = dr * w4r - di * w4i; xi[7] = dr * w4i + di * w4r;
}

__global__ __launch_bounds__(NTHREADS, 2) void ssknplr_kernel(
    const float* __restrict__ log_dt,
    const float* __restrict__ w_re, const float* __restrict__ w_im,
    const float* __restrict__ B_re, const float* __restrict__ B_im,
    const float* __restrict__ P_re, const float* __restrict__ P_im,
    const float* __restrict__ C_re, const float* __restrict__ C_im,
    float* __restrict__ out)
{
    // UN-duplicated per-pole scalars (all v* dt-folded):
    // q0 = {-wi, -wr, wr2, v00r}; q1 = {v00i, v01r, v01i, v10r}; q2 = {v10i, v11}
    __shared__ float4 s_q0[NN];
    __shared__ float4 s_q1[NN];
    __shared__ float2 s_q2[NN];
    __shared__ float2 s_Z[ZP(MM - 1) + 1];   // 2182 float2 ~ 17.5 KB

    const int h   = blockIdx.x;
    const int tid = threadIdx.x;

    // ---- phase 1: per-head pole data ----
    if (tid < NN) {
        const int n   = tid;
        const int idx = h * NN + n;
        const float dt = expf(log_dt[h]);
        const float wr = w_re[idx] * dt;
        const float wi = w_im[idx] * dt;
        const float Br = B_re[idx], Bi = B_im[idx];
        const float Pr = P_re[idx], Pi = P_im[idx];
        const float Cr = C_re[idx], Ci = C_im[idx];
        const float v00r = dt * (Br * Cr - Bi * Ci);
        const float v00i = dt * (Br * Ci + Bi * Cr);
        const float v01r = dt * (Br * Pr + Bi * Pi);   // B*conj(P)
        const float v01i = dt * (Bi * Pr - Br * Pi);
        const float v10r = dt * (Pr * Cr - Pi * Ci);
        const float v10i = dt * (Pr * Ci + Pi * Cr);
        const float v11  = dt * (Pr * Pr + Pi * Pi);
        s_q0[n] = make_float4(-wi, -wr, wr * wr, v00r);
        s_q1[n] = make_float4(v00i, v01r, v01i, v10r);
        s_q2[n] = make_float2(v10i, v11);
    }
    __syncthreads();

    // ---- phase 2: Cauchy + Woodbury, 4 mirror-pair chains ----
    // chain c: k_c = tid + c*256, bins (k_c, 2048-k_c); tid0 chain A -> (0,1024)
    v2f tvA, tvB, tvC, tvD;
    {
        const float rA = (float)tid         * (1.0f / 8192.0f);
        const float rB = (float)(tid + 256) * (1.0f / 8192.0f);
        const float rC = (float)(tid + 512) * (1.0f / 8192.0f);
        const float rD = (float)(tid + 768) * (1.0f / 8192.0f);
        const float sA = sinr(rA), cA = cosr(rA);
        const float sB = sinr(rB), cB = cosr(rB);
        const float sC = sinr(rC), cC = cosr(rC);
        const float sD = sinr(rD), cD = cosr(rD);
        tvA.x = sA * rcpf(cA);
        tvA.y = (tid == 0) ? 1.0f : cA * rcpf(sA);   // tid0 -> bin 1024 (t=1)
        tvB.x = sB * rcpf(cB);  tvB.y = cB * rcpf(sB);
        tvC.x = sC * rcpf(cC);  tvC.y = cC * rcpf(sC);
        tvD.x = sD * rcpf(cD);  tvD.y = cD * rcpf(sD);
    }

    v2f A00r={0.f,0.f},A00i={0.f,0.f},A01r={0.f,0.f},A01i={0.f,0.f};
    v2f A10r={0.f,0.f},A10i={0.f,0.f},A11r={0.f,0.f},A11i={0.f,0.f};
    v2f B00r={0.f,0.f},B00i={0.f,0.f},B01r={0.f,0.f},B01i={0.f,0.f};
    v2f B10r={0.f,0.f},B10i={0.f,0.f},B11r={0.f,0.f},B11i={0.f,0.f};
    v2f C00r={0.f,0.f},C00i={0.f,0.f},C01r={0.f,0.f},C01i={0.f,0.f};
    v2f C10r={0.f,0.f},C10i={0.f,0.f},C11r={0.f,0.f},C11i={0.f,0.f};
    v2f D00r={0.f,0.f},D00i={0.f,0.f},D01r={0.f,0.f},D01i={0.f,0.f};
    v2f D10r={0.f,0.f},D10i={0.f,0.f},D11r={0.f,0.f},D11i={0.f,0.f};

    #pragma unroll 2
    for (int n = 0; n < NN; ++n) {
        const float4 q0 = s_q0[n];
        const float4 q1 = s_q1[n];
        const float2 q2 = s_q2[n];
        const v2f mwi  = {q0.x, q0.x}, nr   = {q0.y, q0.y}, wr2 = {q0.z, q0.z};
        const v2f v00r = {q0.w, q0.w}, v00i = {q1.x, q1.x};
        const v2f v01r = {q1.y, q1.y}, v01i = {q1.z, q1.z};
        const v2f v10r = {q1.w, q1.w}, v10i = {q2.x, q2.x};
        const v2f v11  = {q2.y, q2.y};
        cauchy_step(tvA, mwi, nr, wr2, v00r, v00i, v01r, v01i, v10r, v10i, v11,
                    A00r, A00i, A01r, A01i, A10r, A10i, A11r, A11i);
        cauchy_step(tvB, mwi, nr, wr2, v00r, v00i, v01r, v01i, v10r, v10i, v11,
                    B00r, B00i, B01r, B01i, B10r, B10i, B11r, B11i);
        cauchy_step(tvC, mwi, nr, wr2, v00r, v00i, v01r, v01i, v10r, v10i, v11,
                    C00r, C00i, C01r, C01i, C10r, C10i, C11r, C11i);
        cauchy_step(tvD, mwi, nr, wr2, v00r, v00i, v01r, v01i, v10r, v10i, v11,
                    D00r, D00i, D01r, D01i, D10r, D10i, D11r, D11i);
    }

    // ---- in-register Hermitian recombination -> Z in LDS ----
    {
        v2f Kr, Ki;
        woodbury_K(tvA, A00r, A00i, A01r, A01i, A10r, A10i, A11r, A11i, Kr, Ki);
        if (tid == 0) {
            float sr = 0.f;
            for (int n = 0; n < NN; ++n) sr += s_q0[n].w;      // v00r
            const float KN = 0.5f * sr;                        // analytic K[2048]
            s_Z[ZP(0)]    = make_float2(0.5f * (Kr.x + KN), 0.5f * (Kr.x - KN));
            s_Z[ZP(1024)] = make_float2(Kr.y, -Ki.y);          // Z[M/2] = conj(K[M/2])
        } else {
            const int k = tid, Mk = MM - tid;
            const float rk = (float)k * (1.0f / 4096.0f);
            const float sk = sinr(rk), ck = cosr(rk);
            const float Pr = 0.5f * (Kr.x + Kr.y), Pi = 0.5f * (Ki.x - Ki.y);
            const float Dr = 0.5f * (Kr.x - Kr.y), Di = 0.5f * (Ki.x + Ki.y);
            const float al = sk * Dr + ck * Di;
            const float be = ck * Dr - sk * Di;
            s_Z[ZP(k)]  = make_float2(Pr - al, Pi + be);
            s_Z[ZP(Mk)] = make_float2(Pr + al, be - Pi);
        }
    }
    #pragma unroll
    for (int c = 1; c < 4; ++c) {
        v2f Kr, Ki;
        if (c == 1) woodbury_K(tvB, B00r,B00i,B01r,B01i,B10r,B10i,B11r,B11i, Kr, Ki);
        else if (c == 2) woodbury_K(tvC, C00r,C00i,C01r,C01i,C10r,C10i,C11r,C11i, Kr, Ki);
        else woodbury_K(tvD, D00r,D00i,D01r,D01i,D10r,D10i,D11r,D11i, Kr, Ki);
        const int k = tid + c * 256, Mk = MM - k;
        const float rk = (float)k * (1.0f / 4096.0f);
        const float sk = sinr(rk), ck = cosr(rk);
        const float Pr = 0.5f * (Kr.x + Kr.y), Pi = 0.5f * (Ki.x - Ki.y);
        const float Dr = 0.5f * (Kr.x - Kr.y), Di = 0.5f * (Ki.x + Ki.y);
        const float al = sk * Dr + ck * Di;
        const float be = ck * Dr - sk * Di;
        s_Z[ZP(k)]  = make_float2(Pr - al, Pi + be);
        s_Z[ZP(Mk)] = make_float2(Pr + al, be - Pi);
    }
    __syncthreads();

    // ---- phase 3: 2048-pt inverse FFT, radix-8,8,8,4 (r8-verified) ----
    float xr[8], xi[8];

    // round 1: stages 10,9,8 (stride 256)
    #pragma unroll
    for (int q = 0; q < 8; ++q) {
        const float2 z = s_Z[ZP(tid + (q << 8))];
        xr[q] = z.x; xi[q] = z.y;
    }
    radix8(xr, xi, (float)tid * (1.0f / 2048.0f));
    #pragma unroll
    for (int q = 0; q < 8; ++q)
        s_Z[ZP(tid + (q << 8))] = make_float2(xr[q], xi[q]);
    __syncthreads();

    // round 2: stages 7,6,5 (blocks of 256, stride 32)
    {
        const int base = ((tid >> 5) << 8) + (tid & 31);
        #pragma unroll
        for (int q = 0; q < 8; ++q) {
            const float2 z = s_Z[ZP(base + (q << 5))];
            xr[q] = z.x; xi[q] = z.y;
        }
        radix8(xr, xi, (float)(tid & 31) * (1.0f / 256.0f));
        #pragma unroll
        for (int q = 0; q < 8; ++q)
            s_Z[ZP(base + (q << 5))] = make_float2(xr[q], xi[q]);
    }
    __syncthreads();

    // round 3: stages 4,3,2 (blocks of 32, stride 4)
    {
        const int base = ((tid >> 2) << 5) + (tid & 3);
        #pragma unroll
        for (int q = 0; q < 8; ++q) {
            const float2 z = s_Z[ZP(base + (q << 2))];
            xr[q] = z.x; xi[q] = z.y;
        }
        radix8(xr, xi, (float)(tid & 3) * (1.0f / 32.0f));
        #pragma unroll
        for (int q = 0; q < 8; ++q)
            s_Z[ZP(base + (q << 2))] = make_float2(xr[q], xi[q]);
    }
    __syncthreads();

    // round 4: stages 1,0 = two radix-4 groups on 8 contiguous points
    {
        const int i0 = tid << 3;
        #pragma unroll
        for (int q = 0; q < 8; ++q) {
            const float2 z = s_Z[ZP(i0 + q)];
            xr[q] = z.x; xi[q] = z.y;
        }
        #pragma unroll
        for (int g = 0; g < 2; ++g) {
            const int o = g * 4;
            const float A0r = xr[o] + xr[o+2],   A0i = xi[o] + xi[o+2];
            const float A1r = xr[o+1] + xr[o+3], A1i = xi[o+1] + xi[o+3];
            const float B0r = xr[o] - xr[o+2],   B0i = xi[o] - xi[o+2];
            const float B1r = -(xi[o+1] - xi[o+3]);      // (p1-p3)*i
            const float B1i =  (xr[o+1] - xr[o+3]);
            xr[o]   = A0r + A1r; xi[o]   = A0i + A1i;
            xr[o+1] = A0r - A1r; xi[o+1] = A0i - A1i;
            xr[o+2] = B0r + B1r; xi[o+2] = B0i + B1i;
            xr[o+3] = B0r - B1r; xi[o+3] = B0i - B1i;
        }
        #pragma unroll
        for (int q = 0; q < 8; ++q)
            s_Z[ZP(i0 + q)] = make_float2(xr[q], xi[q]);
    }
    __syncthreads();

    // ---- output: z[m] = X[bitrev11(m)]; x[2m]=Re/M, x[2m+1]=Im/M ----
    const float scale = 1.0f / (float)MM;
    float2* o2 = (float2*)out + (size_t)h * MM;
    #pragma unroll
    for (int q = 0; q < 8; ++q) {
        const int m = tid + (q << 8);
        const int r = (int)(__brev((unsigned)m) >> 21);
        const float2 z = s_Z[ZP(r)];
        o2[m] = make_float2(z.x * scale, z.y * scale);
    }
}

extern "C" void kernel_launch(void* const* d_in, const int* in_sizes, int n_in,
                              void* d_out, int out_size, void* d_ws, size_t ws_size,
                              hipStream_t stream) {
    const float* log_dt = (const float*)d_in[0];
    const float* w_re   = (const float*)d_in[1];
    const float* w_im   = (const float*)d_in[2];
    const float* B_re   = (const float*)d_in[3];
    const float* B_im   = (const float*)d_in[4];
    const float* P_re   = (const float*)d_in[5];
    const float* P_im   = (const float*)d_in[6];
    const float* C_re   = (const float*)d_in[7];
    const float* C_im   = (const float*)d_in[8];
    float* out = (float*)d_out;

    ssknplr_kernel<<<dim3(HH), dim3(NTHREADS), 0, stream>>>(
        log_dt, w_re, w_im, B_re, B_im, P_re, P_im, C_re, C_im, out);
}

// Round 16
// 34.901 us; speedup vs baseline: 1.2078x; 1.0605x over previous
//
#include <hip/hip_runtime.h>
#include <hip/hip_bf16.h>
#include <math.h>

// S4 SSKernelNPLR, fully fused per-head. 512 threads/block (measured optimum:
// r13=35.0 vs r14 1024thr=42.2 vs r15 256thr=37.0), 4 bins/thread in MIRROR
// PAIRS: chain A = bins (tid, 2048-tid), chain B = (512+tid, 1536-tid), via
// tan/cot identity. In-register Hermitian recombination closes phase 2.
//   phase 1: per-h pole params (dt-folded), un-duplicated 2xfloat4+1xfloat2
//            (3 broadcast LDS reads/pole/wave; v2f splats -> VOP3P op_sel).
//   phase 2: Cauchy + Woodbury, packed fp32 (compiler v_pk_fma_f32; r9 showed
//            inline-asm pk regresses). ONE rcp per pole per chain (product-
//            swap trick), and now one rcp per Woodbury epilogue too.
//   phase 3: 2048-pt radix-2 DIF inverse FFT, two stages per barrier (512
//            butterfly-quads = all threads), on-the-fly HW sin/cos twiddles
//            (revolutions < 0.25). Final s=0 stage fused into output gather.
//   LDS pad: ZP(i)=i+(i>>4)+(i>>8) (r15-measured: bank conflicts halved vs
//            single pad; r0 even -> r0,r0+1 remain ZP-consecutive).
// LDS ~20 KB; grid 512 x 512 thr; 7 barriers.
// Dims hardcoded: H=512, N=64, R=1, CH=1, L=4096.

#define HH   512
#define NN   64
#define LLEN 4096
#define MM   2048
#define NTHREADS 512
#define ZP(i) ((i) + ((i) >> 4) + ((i) >> 8))

typedef float v2f __attribute__((ext_vector_type(2)));

__device__ __forceinline__ float sinr(float r) { return __builtin_amdgcn_sinf(r); }  // sin(2*pi*r)
__device__ __forceinline__ float cosr(float r) { return __builtin_amdgcn_cosf(r); }
__device__ __forceinline__ float rcpf(float x) { return __builtin_amdgcn_rcpf(x); }

__device__ __forceinline__ void cauchy_step(
    const v2f tv, const v2f mwi, const v2f nr, const v2f wr2,
    const v2f v00r, const v2f v00i, const v2f v01r, const v2f v01i,
    const v2f v10r, const v2f v10i, const v2f v11,
    v2f& a00r, v2f& a00i, v2f& a01r, v2f& a01i,
    v2f& a10r, v2f& a10i, v2f& a11r, v2f& a11i)
{
    const v2f dim = __builtin_elementwise_fma(tv, (v2f){2.0f, 2.0f}, mwi); // 2t - wi
    const v2f den = __builtin_elementwise_fma(dim, dim, wr2);
    const float ip = rcpf(den.x * den.y);      // one rcp for both halves
    v2f inv; inv.x = den.y * ip; inv.y = den.x * ip;
    const v2f ur = nr * inv;
    const v2f ui = -(dim * inv);
    a00r = __builtin_elementwise_fma( v00r, ur, a00r);
    a00r = __builtin_elementwise_fma(-v00i, ui, a00r);
    a00i = __builtin_elementwise_fma( v00r, ui, a00i);
    a00i = __builtin_elementwise_fma( v00i, ur, a00i);
    a01r = __builtin_elementwise_fma( v01r, ur, a01r);
    a01r = __builtin_elementwise_fma(-v01i, ui, a01r);
    a01i = __builtin_elementwise_fma( v01r, ui, a01i);
    a01i = __builtin_elementwise_fma( v01i, ur, a01i);
    a10r = __builtin_elementwise_fma( v10r, ur, a10r);
    a10r = __builtin_elementwise_fma(-v10i, ui, a10r);
    a10i = __builtin_elementwise_fma( v10r, ui, a10i);
    a10i = __builtin_elementwise_fma( v10i, ur, a10i);
    a11r = __builtin_elementwise_fma( v11,  ur, a11r);
    a11i = __builtin_elementwise_fma( v11,  ui, a11i);
}

__device__ __forceinline__ void woodbury_K(
    const v2f tv,
    const v2f a00r, const v2f a00i, const v2f a01r, const v2f a01i,
    const v2f a10r, const v2f a10i, const v2f a11r, const v2f a11i,
    v2f& Kr, v2f& Ki)
{
    const v2f dr = a11r + 1.0f;
    const v2f di = a11i;
    const v2f dd = __builtin_elementwise_fma(dr, dr, di * di);
    const float ip = rcpf(dd.x * dd.y);        // one rcp for both halves
    v2f dinv; dinv.x = dd.y * ip; dinv.y = dd.x * ip;
    const v2f numr = a01r * a10r - a01i * a10i;
    const v2f numi = a01r * a10i + a01i * a10r;
    const v2f cr = (numr * dr + numi * di) * dinv;
    const v2f ci = (numi * dr - numr * di) * dinv;
    const v2f Wr = a00r - cr;
    const v2f Wi = a00i - ci;
    Kr = __builtin_elementwise_fma(-tv, Wi, Wr);   // K = W * (1 + i*t)
    Ki = __builtin_elementwise_fma( tv, Wr, Wi);
}

__global__ __launch_bounds__(NTHREADS, 4) void ssknplr_kernel(
    const float* __restrict__ log_dt,
    const float* __restrict__ w_re, const float* __restrict__ w_im,
    const float* __restrict__ B_re, const float* __restrict__ B_im,
    const float* __restrict__ P_re, const float* __restrict__ P_im,
    const float* __restrict__ C_re, const float* __restrict__ C_im,
    float* __restrict__ out)
{
    // UN-duplicated per-pole scalars (all v* dt-folded):
    // q0 = {-wi, -wr, wr2, v00r}; q1 = {v00i, v01r, v01i, v10r}; q2 = {v10i, v11}
    __shared__ float4 s_q0[NN];             // 1 KB
    __shared__ float4 s_q1[NN];             // 1 KB
    __shared__ float2 s_q2[NN];             // 0.5 KB
    __shared__ float2 s_Z[ZP(MM - 1) + 1];  // ~17.5 KB padded spectrum

    const int h   = blockIdx.x;
    const int tid = threadIdx.x;

    // ---- phase 1: per-head pole data ----
    if (tid < NN) {
        const int n   = tid;
        const int idx = h * NN + n;
        const float dt = expf(log_dt[h]);
        const float wr = w_re[idx] * dt;
        const float wi = w_im[idx] * dt;
        const float Br = B_re[idx], Bi = B_im[idx];
        const float Pr = P_re[idx], Pi = P_im[idx];
        const float Cr = C_re[idx], Ci = C_im[idx];
        const float v00r = dt * (Br * Cr - Bi * Ci);
        const float v00i = dt * (Br * Ci + Bi * Cr);
        const float v01r = dt * (Br * Pr + Bi * Pi);   // B*conj(P)
        const float v01i = dt * (Bi * Pr - Br * Pi);
        const float v10r = dt * (Pr * Cr - Pi * Ci);
        const float v10i = dt * (Pr * Ci + Pi * Cr);
        const float v11  = dt * (Pr * Pr + Pi * Pi);
        s_q0[n] = make_float4(-wi, -wr, wr * wr, v00r);
        s_q1[n] = make_float4(v00i, v01r, v01i, v10r);
        s_q2[n] = make_float2(v10i, v11);
    }
    __syncthreads();

    // ---- phase 2: Cauchy + Woodbury, mirror-pair chains ----
    // chain A: bins (tid, 2048-tid)   [tid==0: (0, 1024)]
    // chain B: bins (512+tid, 1536-tid)
    v2f tvA, tvB;
    {
        const float rA = (float)tid         * (1.0f / 8192.0f);
        const float rB = (float)(tid + 512) * (1.0f / 8192.0f);
        const float sA = sinr(rA), cA = cosr(rA);
        const float sB = sinr(rB), cB = cosr(rB);
        tvA.x = sA * rcpf(cA);                              // tan
        tvA.y = (tid == 0) ? 1.0f : cA * rcpf(sA);          // cot; tid0 -> bin 1024
        tvB.x = sB * rcpf(cB);
        tvB.y = cB * rcpf(sB);
    }

    v2f A00r = {0.f,0.f}, A00i = {0.f,0.f}, A01r = {0.f,0.f}, A01i = {0.f,0.f};
    v2f A10r = {0.f,0.f}, A10i = {0.f,0.f}, A11r = {0.f,0.f}, A11i = {0.f,0.f};
    v2f B00r = {0.f,0.f}, B00i = {0.f,0.f}, B01r = {0.f,0.f}, B01i = {0.f,0.f};
    v2f B10r = {0.f,0.f}, B10i = {0.f,0.f}, B11r = {0.f,0.f}, B11i = {0.f,0.f};

    #pragma unroll 4
    for (int n = 0; n < NN; ++n) {
        const float4 q0 = s_q0[n];
        const float4 q1 = s_q1[n];
        const float2 q2 = s_q2[n];
        // v2f splats: folded into VOP3P op_sel (no movs expected)
        const v2f mwi  = {q0.x, q0.x}, nr   = {q0.y, q0.y}, wr2 = {q0.z, q0.z};
        const v2f v00r = {q0.w, q0.w}, v00i = {q1.x, q1.x};
        const v2f v01r = {q1.y, q1.y}, v01i = {q1.z, q1.z};
        const v2f v10r = {q1.w, q1.w}, v10i = {q2.x, q2.x};
        const v2f v11  = {q2.y, q2.y};
        cauchy_step(tvA, mwi, nr, wr2, v00r, v00i, v01r, v01i, v10r, v10i, v11,
                    A00r, A00i, A01r, A01i, A10r, A10i, A11r, A11i);
        cauchy_step(tvB, mwi, nr, wr2, v00r, v00i, v01r, v01i, v10r, v10i, v11,
                    B00r, B00i, B01r, B01i, B10r, B10i, B11r, B11i);
    }

    // ---- in-register Hermitian recombination -> Z ----
    {
        v2f Kr, Ki;
        woodbury_K(tvA, A00r, A00i, A01r, A01i, A10r, A10i, A11r, A11i, Kr, Ki);
        if (tid == 0) {
            float sr = 0.f;
            for (int n = 0; n < NN; ++n) sr += s_q0[n].w;      // v00r
            const float KN = 0.5f * sr;                        // analytic Nyquist K[2048]
            s_Z[ZP(0)]    = make_float2(0.5f * (Kr.x + KN), 0.5f * (Kr.x - KN));
            s_Z[ZP(1024)] = make_float2(Kr.y, -Ki.y);          // Z[M/2] = conj(K[M/2])
        } else {
            const int k = tid, Mk = MM - tid;
            const float rk = (float)k * (1.0f / 4096.0f);
            const float sk = sinr(rk), ck = cosr(rk);
            const float Pr = 0.5f * (Kr.x + Kr.y), Pi = 0.5f * (Ki.x - Ki.y);
            const float Dr = 0.5f * (Kr.x - Kr.y), Di = 0.5f * (Ki.x + Ki.y);
            const float al = sk * Dr + ck * Di;
            const float be = ck * Dr - sk * Di;
            s_Z[ZP(k)]  = make_float2(Pr - al, Pi + be);
            s_Z[ZP(Mk)] = make_float2(Pr + al, be - Pi);
        }
    }
    {
        v2f Kr, Ki;
        woodbury_K(tvB, B00r, B00i, B01r, B01i, B10r, B10i, B11r, B11i, Kr, Ki);
        const int k = 512 + tid, Mk = 1536 - tid;
        const float rk = (float)k * (1.0f / 4096.0f);
        const float sk = sinr(rk), ck = cosr(rk);
        const float Pr = 0.5f * (Kr.x + Kr.y), Pi = 0.5f * (Ki.x - Ki.y);
        const float Dr = 0.5f * (Kr.x - Kr.y), Di = 0.5f * (Ki.x + Ki.y);
        const float al = sk * Dr + ck * Di;
        const float be = ck * Dr - sk * Di;
        s_Z[ZP(k)]  = make_float2(Pr - al, Pi + be);
        s_Z[ZP(Mk)] = make_float2(Pr + al, be - Pi);
    }
    __syncthreads();

    // ---- phase 3: 2048-pt inverse FFT, radix-2 DIF, TWO stages per barrier ----
    // Rounds (10,9)(8,7)(6,5)(4,3)(2,1); stage 0 fused into the output.
    for (int s = 10; s >= 1; s -= 2) {
        const int H = 1 << s;
        const int Q = H >> 1;
        const float scale = rcpf((float)(2 * H));           // exact pow2
        {
            const int b    = tid;
            const int j    = b & (Q - 1);
            const int base = ((b >> (s - 1)) << (s + 1)) + j;
            const int i0 = base, i1 = base + Q, i2 = base + H, i3 = base + H + Q;
            const float rev = (float)j * scale;             // < 0.25
            const float c  = cosr(rev);
            const float sn = sinr(rev);
            const float wbr = c * c - sn * sn;              // wB = wA^2
            const float wbi = 2.0f * c * sn;
            const float2 u0 = s_Z[ZP(i0)];
            const float2 u1 = s_Z[ZP(i1)];
            const float2 u2 = s_Z[ZP(i2)];
            const float2 u3 = s_Z[ZP(i3)];
            // level A (stage s): (i0,i2) with wA ; (i1,i3) with i*wA
            const float a0r = u0.x + u2.x, a0i = u0.y + u2.y;
            const float d0r = u0.x - u2.x, d0i = u0.y - u2.y;
            const float a1r = u1.x + u3.x, a1i = u1.y + u3.y;
            const float d1r = u1.x - u3.x, d1i = u1.y - u3.y;
            const float e0r = d0r * c  - d0i * sn, e0i = d0r * sn + d0i * c;
            const float e1r = -(d1r * sn) - d1i * c, e1i = d1r * c - d1i * sn;
            // level B (stage s-1): (i0,i1) and (i2,i3), both with wB
            s_Z[ZP(i0)] = make_float2(a0r + a1r, a0i + a1i);
            const float t0r = a0r - a1r, t0i = a0i - a1i;
            s_Z[ZP(i1)] = make_float2(t0r * wbr - t0i * wbi, t0r * wbi + t0i * wbr);
            s_Z[ZP(i2)] = make_float2(e0r + e1r, e0i + e1i);
            const float t1r = e0r - e1r, t1i = e0i - e1i;
            s_Z[ZP(i3)] = make_float2(t1r * wbr - t1i * wbi, t1r * wbi + t1i * wbr);
        }
        __syncthreads();
    }

    // ---- output with FUSED final stage ----
    // m = tid + q*512 -> r = bitrev11(m) = r0 | {q0:0, q1:2, q2:1, q3:3},
    // r0 = bitrev11(tid) (bits 0-1 clear):
    //   out[tid]=z0+z1, out[tid+512]=z2+z3, out[tid+1024]=z0-z1,
    //   out[tid+1536]=z2-z3 (all * 1/M); r0..r0+3 stay ZP-consecutive
    //   (r0 = 4a, so bits 0-1 never carry into the pad terms).
    {
        const float scale = 1.0f / (float)MM;
        const int r0 = (int)(__brev((unsigned)tid) >> 21);  // bits 0-1 clear
        const int zb = ZP(r0);
        const float2 z0 = s_Z[zb + 0];
        const float2 z1 = s_Z[zb + 1];
        const float2 z2 = s_Z[zb + 2];
        const float2 z3 = s_Z[zb + 3];
        float2* o2 = (float2*)out + (size_t)h * MM;
        o2[tid]        = make_float2((z0.x + z1.x) * scale, (z0.y + z1.y) * scale);
        o2[tid + 512]  = make_float2((z2.x + z3.x) * scale, (z2.y + z3.y) * scale);
        o2[tid + 1024] = make_float2((z0.x - z1.x) * scale, (z0.y - z1.y) * scale);
        o2[tid + 1536] = make_float2((z2.x - z3.x) * scale, (z2.y - z3.y) * scale);
    }
}

extern "C" void kernel_launch(void* const* d_in, const int* in_sizes, int n_in,
                              void* d_out, int out_size, void* d_ws, size_t ws_size,
                              hipStream_t stream) {
    const float* log_dt = (const float*)d_in[0];
    const float* w_re   = (const float*)d_in[1];
    const float* w_im   = (const float*)d_in[2];
    const float* B_re   = (const float*)d_in[3];
    const float* B_im   = (const float*)d_in[4];
    const float* P_re   = (const float*)d_in[5];
    const float* P_im   = (const float*)d_in[6];
    const float* C_re   = (const float*)d_in[7];
    const float* C_im   = (const float*)d_in[8];
    float* out = (float*)d_out;

    ssknplr_kernel<<<dim3(HH), dim3(NTHREADS), 0, stream>>>(
        log_dt, w_re, w_im, B_re, B_im, P_re, P_im, C_re, C_im, out);
}

// Round 17
// 34.780 us; speedup vs baseline: 1.2120x; 1.0035x over previous
//
#include <hip/hip_runtime.h>
#include <hip/hip_bf16.h>
#include <math.h>

// S4 SSKernelNPLR, fully fused per-head. 512 threads/block (measured optimum:
// r13=35.0 vs r14 1024thr=42.2 vs r15 256thr=37.0), 4 bins/thread in MIRROR
// PAIRS: chain A = bins (tid, 2048-tid), chain B = (512+tid, 1536-tid), via
// tan/cot identity. In-register Hermitian recombination closes phase 2.
//   phase 1: per-h pole params (dt-folded), un-duplicated 2xfloat4+1xfloat2
//            (3 broadcast LDS reads/pole/wave; v2f splats -> VOP3P op_sel).
//   phase 2: Cauchy + Woodbury, packed fp32 (compiler v_pk_fma_f32; r9 showed
//            inline-asm pk regresses). ONE rcp per pole per chain and per
//            Woodbury epilogue (product-swap trick).
//   phase 3: 2048-pt radix-2 DIF inverse FFT, two stages per round.
//            Rounds (10,9)(8,7): block-wide, barriered. Rounds (6,5)(4,3)(2,1):
//            WAVE-LOCAL -- spans <=64 confine each wave to its private
//            256-elem region [256w,256w+256) (index algebra verified for
//            s=6/4/2), so wave64 lockstep + in-order per-wave LDS pipe
//            replace s_barrier with a free compiler fence (wave_barrier).
//            Barriers: 7 -> 4. Final s=0 stage fused into output gather.
//   LDS pad: ZP(i)=i+(i>>4)+(i>>8) (r15-measured: conflicts halved).
// LDS ~20 KB; grid 512 x 512 thr.
// Dims hardcoded: H=512, N=64, R=1, CH=1, L=4096.

#define HH   512
#define NN   64
#define LLEN 4096
#define MM   2048
#define NTHREADS 512
#define ZP(i) ((i) + ((i) >> 4) + ((i) >> 8))

typedef float v2f __attribute__((ext_vector_type(2)));

__device__ __forceinline__ float sinr(float r) { return __builtin_amdgcn_sinf(r); }  // sin(2*pi*r)
__device__ __forceinline__ float cosr(float r) { return __builtin_amdgcn_cosf(r); }
__device__ __forceinline__ float rcpf(float x) { return __builtin_amdgcn_rcpf(x); }

__device__ __forceinline__ void cauchy_step(
    const v2f tv, const v2f mwi, const v2f nr, const v2f wr2,
    const v2f v00r, const v2f v00i, const v2f v01r, const v2f v01i,
    const v2f v10r, const v2f v10i, const v2f v11,
    v2f& a00r, v2f& a00i, v2f& a01r, v2f& a01i,
    v2f& a10r, v2f& a10i, v2f& a11r, v2f& a11i)
{
    const v2f dim = __builtin_elementwise_fma(tv, (v2f){2.0f, 2.0f}, mwi); // 2t - wi
    const v2f den = __builtin_elementwise_fma(dim, dim, wr2);
    const float ip = rcpf(den.x * den.y);      // one rcp for both halves
    v2f inv; inv.x = den.y * ip; inv.y = den.x * ip;
    const v2f ur = nr * inv;
    const v2f ui = -(dim * inv);
    a00r = __builtin_elementwise_fma( v00r, ur, a00r);
    a00r = __builtin_elementwise_fma(-v00i, ui, a00r);
    a00i = __builtin_elementwise_fma( v00r, ui, a00i);
    a00i = __builtin_elementwise_fma( v00i, ur, a00i);
    a01r = __builtin_elementwise_fma( v01r, ur, a01r);
    a01r = __builtin_elementwise_fma(-v01i, ui, a01r);
    a01i = __builtin_elementwise_fma( v01r, ui, a01i);
    a01i = __builtin_elementwise_fma( v01i, ur, a01i);
    a10r = __builtin_elementwise_fma( v10r, ur, a10r);
    a10r = __builtin_elementwise_fma(-v10i, ui, a10r);
    a10i = __builtin_elementwise_fma( v10r, ui, a10i);
    a10i = __builtin_elementwise_fma( v10i, ur, a10i);
    a11r = __builtin_elementwise_fma( v11,  ur, a11r);
    a11i = __builtin_elementwise_fma( v11,  ui, a11i);
}

__device__ __forceinline__ void woodbury_K(
    const v2f tv,
    const v2f a00r, const v2f a00i, const v2f a01r, const v2f a01i,
    const v2f a10r, const v2f a10i, const v2f a11r, const v2f a11i,
    v2f& Kr, v2f& Ki)
{
    const v2f dr = a11r + 1.0f;
    const v2f di = a11i;
    const v2f dd = __builtin_elementwise_fma(dr, dr, di * di);
    const float ip = rcpf(dd.x * dd.y);        // one rcp for both halves
    v2f dinv; dinv.x = dd.y * ip; dinv.y = dd.x * ip;
    const v2f numr = a01r * a10r - a01i * a10i;
    const v2f numi = a01r * a10i + a01i * a10r;
    const v2f cr = (numr * dr + numi * di) * dinv;
    const v2f ci = (numi * dr - numr * di) * dinv;
    const v2f Wr = a00r - cr;
    const v2f Wi = a00i - ci;
    Kr = __builtin_elementwise_fma(-tv, Wi, Wr);   // K = W * (1 + i*t)
    Ki = __builtin_elementwise_fma( tv, Wr, Wi);
}

__global__ __launch_bounds__(NTHREADS, 4) void ssknplr_kernel(
    const float* __restrict__ log_dt,
    const float* __restrict__ w_re, const float* __restrict__ w_im,
    const float* __restrict__ B_re, const float* __restrict__ B_im,
    const float* __restrict__ P_re, const float* __restrict__ P_im,
    const float* __restrict__ C_re, const float* __restrict__ C_im,
    float* __restrict__ out)
{
    // UN-duplicated per-pole scalars (all v* dt-folded):
    // q0 = {-wi, -wr, wr2, v00r}; q1 = {v00i, v01r, v01i, v10r}; q2 = {v10i, v11}
    __shared__ float4 s_q0[NN];             // 1 KB
    __shared__ float4 s_q1[NN];             // 1 KB
    __shared__ float2 s_q2[NN];             // 0.5 KB
    __shared__ float2 s_Z[ZP(MM - 1) + 1];  // ~17.5 KB padded spectrum

    const int h   = blockIdx.x;
    const int tid = threadIdx.x;

    // ---- phase 1: per-head pole data ----
    if (tid < NN) {
        const int n   = tid;
        const int idx = h * NN + n;
        const float dt = expf(log_dt[h]);
        const float wr = w_re[idx] * dt;
        const float wi = w_im[idx] * dt;
        const float Br = B_re[idx], Bi = B_im[idx];
        const float Pr = P_re[idx], Pi = P_im[idx];
        const float Cr = C_re[idx], Ci = C_im[idx];
        const float v00r = dt * (Br * Cr - Bi * Ci);
        const float v00i = dt * (Br * Ci + Bi * Cr);
        const float v01r = dt * (Br * Pr + Bi * Pi);   // B*conj(P)
        const float v01i = dt * (Bi * Pr - Br * Pi);
        const float v10r = dt * (Pr * Cr - Pi * Ci);
        const float v10i = dt * (Pr * Ci + Pi * Cr);
        const float v11  = dt * (Pr * Pr + Pi * Pi);
        s_q0[n] = make_float4(-wi, -wr, wr * wr, v00r);
        s_q1[n] = make_float4(v00i, v01r, v01i, v10r);
        s_q2[n] = make_float2(v10i, v11);
    }
    __syncthreads();

    // ---- phase 2: Cauchy + Woodbury, mirror-pair chains ----
    // chain A: bins (tid, 2048-tid)   [tid==0: (0, 1024)]
    // chain B: bins (512+tid, 1536-tid)
    v2f tvA, tvB;
    {
        const float rA = (float)tid         * (1.0f / 8192.0f);
        const float rB = (float)(tid + 512) * (1.0f / 8192.0f);
        const float sA = sinr(rA), cA = cosr(rA);
        const float sB = sinr(rB), cB = cosr(rB);
        tvA.x = sA * rcpf(cA);                              // tan
        tvA.y = (tid == 0) ? 1.0f : cA * rcpf(sA);          // cot; tid0 -> bin 1024
        tvB.x = sB * rcpf(cB);
        tvB.y = cB * rcpf(sB);
    }

    v2f A00r = {0.f,0.f}, A00i = {0.f,0.f}, A01r = {0.f,0.f}, A01i = {0.f,0.f};
    v2f A10r = {0.f,0.f}, A10i = {0.f,0.f}, A11r = {0.f,0.f}, A11i = {0.f,0.f};
    v2f B00r = {0.f,0.f}, B00i = {0.f,0.f}, B01r = {0.f,0.f}, B01i = {0.f,0.f};
    v2f B10r = {0.f,0.f}, B10i = {0.f,0.f}, B11r = {0.f,0.f}, B11i = {0.f,0.f};

    #pragma unroll 4
    for (int n = 0; n < NN; ++n) {
        const float4 q0 = s_q0[n];
        const float4 q1 = s_q1[n];
        const float2 q2 = s_q2[n];
        // v2f splats: folded into VOP3P op_sel (no movs expected)
        const v2f mwi  = {q0.x, q0.x}, nr   = {q0.y, q0.y}, wr2 = {q0.z, q0.z};
        const v2f v00r = {q0.w, q0.w}, v00i = {q1.x, q1.x};
        const v2f v01r = {q1.y, q1.y}, v01i = {q1.z, q1.z};
        const v2f v10r = {q1.w, q1.w}, v10i = {q2.x, q2.x};
        const v2f v11  = {q2.y, q2.y};
        cauchy_step(tvA, mwi, nr, wr2, v00r, v00i, v01r, v01i, v10r, v10i, v11,
                    A00r, A00i, A01r, A01i, A10r, A10i, A11r, A11i);
        cauchy_step(tvB, mwi, nr, wr2, v00r, v00i, v01r, v01i, v10r, v10i, v11,
                    B00r, B00i, B01r, B01i, B10r, B10i, B11r, B11i);
    }

    // ---- in-register Hermitian recombination -> Z ----
    {
        v2f Kr, Ki;
        woodbury_K(tvA, A00r, A00i, A01r, A01i, A10r, A10i, A11r, A11i, Kr, Ki);
        if (tid == 0) {
            float sr = 0.f;
            for (int n = 0; n < NN; ++n) sr += s_q0[n].w;      // v00r
            const float KN = 0.5f * sr;                        // analytic Nyquist K[2048]
            s_Z[ZP(0)]    = make_float2(0.5f * (Kr.x + KN), 0.5f * (Kr.x - KN));
            s_Z[ZP(1024)] = make_float2(Kr.y, -Ki.y);          // Z[M/2] = conj(K[M/2])
        } else {
            const int k = tid, Mk = MM - tid;
            const float rk = (float)k * (1.0f / 4096.0f);
            const float sk = sinr(rk), ck = cosr(rk);
            const float Pr = 0.5f * (Kr.x + Kr.y), Pi = 0.5f * (Ki.x - Ki.y);
            const float Dr = 0.5f * (Kr.x - Kr.y), Di = 0.5f * (Ki.x + Ki.y);
            const float al = sk * Dr + ck * Di;
            const float be = ck * Dr - sk * Di;
            s_Z[ZP(k)]  = make_float2(Pr - al, Pi + be);
            s_Z[ZP(Mk)] = make_float2(Pr + al, be - Pi);
        }
    }
    {
        v2f Kr, Ki;
        woodbury_K(tvB, B00r, B00i, B01r, B01i, B10r, B10i, B11r, B11i, Kr, Ki);
        const int k = 512 + tid, Mk = 1536 - tid;
        const float rk = (float)k * (1.0f / 4096.0f);
        const float sk = sinr(rk), ck = cosr(rk);
        const float Pr = 0.5f * (Kr.x + Kr.y), Pi = 0.5f * (Ki.x - Ki.y);
        const float Dr = 0.5f * (Kr.x - Kr.y), Di = 0.5f * (Ki.x + Ki.y);
        const float al = sk * Dr + ck * Di;
        const float be = ck * Dr - sk * Di;
        s_Z[ZP(k)]  = make_float2(Pr - al, Pi + be);
        s_Z[ZP(Mk)] = make_float2(Pr + al, be - Pi);
    }
    __syncthreads();

    // ---- phase 3: 2048-pt inverse FFT, radix-2 DIF, two stages per round ----
    // Rounds (10,9)(8,7): block-wide with s_barrier.
    #pragma unroll
    for (int s = 10; s >= 7; s -= 2) {
        const int H = 1 << s;
        const int Q = H >> 1;
        const float scale = rcpf((float)(2 * H));           // exact pow2
        {
            const int b    = tid;
            const int j    = b & (Q - 1);
            const int base = ((b >> (s - 1)) << (s + 1)) + j;
            const int i0 = base, i1 = base + Q, i2 = base + H, i3 = base + H + Q;
            const float rev = (float)j * scale;             // < 0.25
            const float c  = cosr(rev);
            const float sn = sinr(rev);
            const float wbr = c * c - sn * sn;              // wB = wA^2
            const float wbi = 2.0f * c * sn;
            const float2 u0 = s_Z[ZP(i0)];
            const float2 u1 = s_Z[ZP(i1)];
            const float2 u2 = s_Z[ZP(i2)];
            const float2 u3 = s_Z[ZP(i3)];
            const float a0r = u0.x + u2.x, a0i = u0.y + u2.y;
            const float d0r = u0.x - u2.x, d0i = u0.y - u2.y;
            const float a1r = u1.x + u3.x, a1i = u1.y + u3.y;
            const float d1r = u1.x - u3.x, d1i = u1.y - u3.y;
            const float e0r = d0r * c  - d0i * sn, e0i = d0r * sn + d0i * c;
            const float e1r = -(d1r * sn) - d1i * c, e1i = d1r * c - d1i * sn;
            s_Z[ZP(i0)] = make_float2(a0r + a1r, a0i + a1i);
            const float t0r = a0r - a1r, t0i = a0i - a1i;
            s_Z[ZP(i1)] = make_float2(t0r * wbr - t0i * wbi, t0r * wbi + t0i * wbr);
            s_Z[ZP(i2)] = make_float2(e0r + e1r, e0i + e1i);
            const float t1r = e0r - e1r, t1i = e0i - e1i;
            s_Z[ZP(i3)] = make_float2(t1r * wbr - t1i * wbi, t1r * wbi + t1i * wbr);
        }
        __syncthreads();
    }

    // Rounds (6,5)(4,3)(2,1): spans <= 64 -> wave w touches only its private
    // region [256w, 256w+256) (verified for s=6/4/2 index algebra). Wave64
    // lockstep + in-order per-wave LDS pipe => no s_barrier needed; the
    // wave_barrier() is a free compiler reordering fence.
    #pragma unroll
    for (int s = 6; s >= 1; s -= 2) {
        const int H = 1 << s;
        const int Q = H >> 1;
        const float scale = rcpf((float)(2 * H));           // exact pow2
        {
            const int b    = tid;
            const int j    = b & (Q - 1);
            const int base = ((b >> (s - 1)) << (s + 1)) + j;
            const int i0 = base, i1 = base + Q, i2 = base + H, i3 = base + H + Q;
            const float rev = (float)j * scale;             // < 0.25
            const float c  = cosr(rev);
            const float sn = sinr(rev);
            const float wbr = c * c - sn * sn;              // wB = wA^2
            const float wbi = 2.0f * c * sn;
            const float2 u0 = s_Z[ZP(i0)];
            const float2 u1 = s_Z[ZP(i1)];
            const float2 u2 = s_Z[ZP(i2)];
            const float2 u3 = s_Z[ZP(i3)];
            const float a0r = u0.x + u2.x, a0i = u0.y + u2.y;
            const float d0r = u0.x - u2.x, d0i = u0.y - u2.y;
            const float a1r = u1.x + u3.x, a1i = u1.y + u3.y;
            const float d1r = u1.x - u3.x, d1i = u1.y - u3.y;
            const float e0r = d0r * c  - d0i * sn, e0i = d0r * sn + d0i * c;
            const float e1r = -(d1r * sn) - d1i * c, e1i = d1r * c - d1i * sn;
            s_Z[ZP(i0)] = make_float2(a0r + a1r, a0i + a1i);
            const float t0r = a0r - a1r, t0i = a0i - a1i;
            s_Z[ZP(i1)] = make_float2(t0r * wbr - t0i * wbi, t0r * wbi + t0i * wbr);
            s_Z[ZP(i2)] = make_float2(e0r + e1r, e0i + e1i);
            const float t1r = e0r - e1r, t1i = e0i - e1i;
            s_Z[ZP(i3)] = make_float2(t1r * wbr - t1i * wbi, t1r * wbi + t1i * wbr);
        }
        __builtin_amdgcn_wave_barrier();   // compile-time fence only (no s_barrier)
    }
    __syncthreads();   // regions complete before the bitrev-scattered gather

    // ---- output with FUSED final stage ----
    // m = tid + q*512 -> r = bitrev11(m) = r0 | {q0:0, q1:2, q2:1, q3:3},
    // r0 = bitrev11(tid) (bits 0-1 clear):
    //   out[tid]=z0+z1, out[tid+512]=z2+z3, out[tid+1024]=z0-z1,
    //   out[tid+1536]=z2-z3 (all * 1/M); r0..r0+3 stay ZP-consecutive
    //   (r0 = 4a, so bits 0-1 never carry into the pad terms).
    {
        const float scale = 1.0f / (float)MM;
        const int r0 = (int)(__brev((unsigned)tid) >> 21);  // bits 0-1 clear
        const int zb = ZP(r0);
        const float2 z0 = s_Z[zb + 0];
        const float2 z1 = s_Z[zb + 1];
        const float2 z2 = s_Z[zb + 2];
        const float2 z3 = s_Z[zb + 3];
        float2* o2 = (float2*)out + (size_t)h * MM;
        o2[tid]        = make_float2((z0.x + z1.x) * scale, (z0.y + z1.y) * scale);
        o2[tid + 512]  = make_float2((z2.x + z3.x) * scale, (z2.y + z3.y) * scale);
        o2[tid + 1024] = make_float2((z0.x - z1.x) * scale, (z0.y - z1.y) * scale);
        o2[tid + 1536] = make_float2((z2.x - z3.x) * scale, (z2.y - z3.y) * scale);
    }
}

extern "C" void kernel_launch(void* const* d_in, const int* in_sizes, int n_in,
                              void* d_out, int out_size, void* d_ws, size_t ws_size,
                              hipStream_t stream) {
    const float* log_dt = (const float*)d_in[0];
    const float* w_re   = (const float*)d_in[1];
    const float* w_im   = (const float*)d_in[2];
    const float* B_re   = (const float*)d_in[3];
    const float* B_im   = (const float*)d_in[4];
    const float* P_re   = (const float*)d_in[5];
    const float* P_im   = (const float*)d_in[6];
    const float* C_re   = (const float*)d_in[7];
    const float* C_im   = (const float*)d_in[8];
    float* out = (float*)d_out;

    ssknplr_kernel<<<dim3(HH), dim3(NTHREADS), 0, stream>>>(
        log_dt, w_re, w_im, B_re, B_im, P_re, P_im, C_re, C_im, out);
}